// Round 3
// baseline (516.993 us; speedup 1.0000x reference)
//
#include <hip/hip_runtime.h>

// Problem constants: B=64, C=256, H=W=28, N=784
#define BB   64
#define CC   256
#define NPIX 784
#define SLOTS 128

// ---------------------------------------------------------------------------
// Fused masked-cosine-sim kernel. zt_k is GONE: each block stages the z
// columns it needs directly from the untransposed z[b,C,N] into an LDS slab.
//
// Block = (loss, b, row, half): 14 consecutive i's of ONE grid row.
//  - all i in a row share the same float g1y  -> identical jy0 (bit-exact)
//    -> the block's candidate j's span exactly rows [JR0, JR0+2].
//  - cx is monotone in i_x (scales > 0) -> col union <= 20 starting at
//    JCL = jx0(first i).  Slab = 3 rows x 20 cols x 256 ch = 62 KB LDS.
// Staging clamps row/col to 27 (duplicate slots are never read: the
// bit-exact mask only passes j's inside each i's true box).
//
// Grid 7168 = 8 xcd * 2 loss * 8 b8 * 56 tile, bid%8 == b%8 so all 56
// blocks of one (loss,b) land on one XCD -> slab gather overfetch is
// absorbed by that XCD's L2 (z[b]+y[b] = 1.6 MB << 4 MB).
//
// Dot-product lane->channel map, FMA chains, na reduce, mask math: all
// byte-identical to the verified R2 kernel. Only nb2's summation order
// changes (precedent: R1->R2 reordered zn2, absmax stayed 0.0).
// ---------------------------------------------------------------------------
__global__ __launch_bounds__(896, 7) void pairs_k(
    const float* __restrict__ y1, const float* __restrict__ y2,
    const float* __restrict__ z1, const float* __restrict__ z2,
    const float* __restrict__ g1g, const float* __restrict__ g2g,
    double* __restrict__ acc) {
    __shared__ float  slab[60 * 260];   // [slot s = ry*20+k][c], stride 260
    __shared__ float  ylds[14 * 256];   // [i-offset][c]
    __shared__ float  nlds[60];         // per-slot z squared-norms
    __shared__ double shs[14];
    __shared__ int    shc[14];

    int tid  = threadIdx.x;
    int lane = tid & 63, wv = tid >> 6;     // wv 0..13, wave per i
    int bid  = blockIdx.x;
    int xcd  = bid & 7;
    int q    = bid >> 3;                    // 0..895
    int loss = q / 448;
    int rr   = q - loss * 448;              // 0..447
    int b8   = rr / 56;
    int tile = rr - b8 * 56;                // 0..55
    int b    = xcd + 8 * b8;
    int row  = tile >> 1, hf = tile & 1;
    int i0   = row * 28 + 14 * hf;          // first of 14 i's

    const float* g1 = g1g + (size_t)b * 2 * NPIX;
    const float* g2 = g2g + (size_t)b * 2 * NPIX;

    // ---- block-uniform box params (bit-exact same chain as per-i mask) ----
    const float* gb = loss ? g2 : g1;
    float d0  = gb[29] - gb[0];
    float d1  = gb[NPIX + 29] - gb[NPIX];
    float bin = __fsqrt_rn(__fadd_rn(__fmul_rn(d0, d0), __fmul_rn(d1, d1)));
    float t2y = g2[0], t2x = g2[NPIX];
    float s2y = g2[28] - g2[0];
    float s2x = g2[NPIX + 1] - g2[NPIX];
    float rV  = 0.7f * bin * 1.0002f + 1e-4f;
    float ryr = rV / s2y + 0.05f;
    float rxr = rV / s2x + 0.05f;
    float cy0 = (g1[i0] - t2y) / s2y;            // same float for all i in row
    int JR0 = max(0, (int)ceilf(cy0 - ryr));     // == every i's jy0
    float cxf = (g1[NPIX + i0] - t2x) / s2x;
    int JCL = max(0, (int)ceilf(cxf - rxr));     // == min over i of jx0

    // ---- stage slab: 3x20 slots x 256 c from z[b], clamped duplicates ----
    const float* Zb = (loss ? z1 : z2) + (size_t)b * CC * NPIX;
#pragma unroll
    for (int m = 0; m < 18; m++) {
        int idx = tid + 896 * m;               // 15360 scalars total
        if (idx < 15360) {
            int c  = idx / 60;
            int s  = idx - c * 60;
            int ry = (s >= 40) ? 2 : ((s >= 20) ? 1 : 0);
            int k  = s - ry * 20;
            int jr = min(JR0 + ry, 27);
            int jc = min(JCL + k, 27);
            slab[s * 260 + c] = Zb[(size_t)c * NPIX + jr * 28 + jc];
        }
    }

    // ---- stage ylds[14][256]: y[b, c, i0..i0+13], aligned float2 ----
    const float* Yg = (loss ? y2 : y1) + (size_t)b * CC * NPIX;
#pragma unroll
    for (int m = 0; m < 2; m++) {
        int idx = tid + 896 * m;               // 1792 float2 total
        if (idx < 1792) {
            int c  = idx / 7;
            int qq = idx - c * 7;
            float2 v = *(const float2*)(Yg + (size_t)c * NPIX + i0 + 2 * qq);
            ylds[(2 * qq + 0) * 256 + c] = v.x;
            ylds[(2 * qq + 1) * 256 + c] = v.y;
        }
    }

    // ---- per-wave mask (byte-identical to verified kernel) ----
    int i = i0 + wv;
    float g1y = g1[i];
    float g1x = g1[NPIX + i];
    float cy = (g1y - t2y) / s2y;
    float cx = (g1x - t2x) / s2x;
    int jy0 = max(0,  (int)ceilf(cy - ryr));
    int jy1 = min(27, (int)floorf(cy + ryr));
    int jx0 = max(0,  (int)ceilf(cx - rxr));
    int jx1 = min(27, (int)floorf(cx + rxr));
    int dyr = jy1 - jy0, dxr = jx1 - jx0;

    int dyl = lane >> 2, dxl = lane & 3;
    bool pass = false;
    if (lane < 16 && dyl <= dyr && dxl <= dxr) {
        int jc = (jy0 + dyl) * 28 + jx0 + dxl;
        float dy = g1y - g2[jc];
        float dx = g1x - g2[NPIX + jc];
        float d  = __fsqrt_rn(__fadd_rn(__fmul_rn(dy, dy), __fmul_rn(dx, dx)));
        pass = (__fdiv_rn(d, bin) <= 0.7f);   // bit-exact mask decision
    }
    unsigned long long mball = __ballot(pass);
    int cnt = __builtin_popcountll(mball);

    __syncthreads();

    // ---- per-slot z norms (16-lane group per slot, 56 groups for 60) ----
    {
        int gid = wv * 4 + (lane >> 4);       // 0..55
        int gl2 = lane & 15;
        for (int s = gid; s < 60; s += 56) {
            const float4* Z4 = (const float4*)(slab + s * 260);
            float4 a = Z4[gl2], b4 = Z4[gl2 + 16], c4 = Z4[gl2 + 32], e4 = Z4[gl2 + 48];
            float pp = a.x * a.x;
            pp = fmaf(a.y, a.y, pp); pp = fmaf(a.z, a.z, pp); pp = fmaf(a.w, a.w, pp);
            pp = fmaf(b4.x, b4.x, pp); pp = fmaf(b4.y, b4.y, pp); pp = fmaf(b4.z, b4.z, pp);
            pp = fmaf(b4.w, b4.w, pp);
            pp = fmaf(c4.x, c4.x, pp); pp = fmaf(c4.y, c4.y, pp); pp = fmaf(c4.z, c4.z, pp);
            pp = fmaf(c4.w, c4.w, pp);
            pp = fmaf(e4.x, e4.x, pp); pp = fmaf(e4.y, e4.y, pp); pp = fmaf(e4.z, e4.z, pp);
            pp = fmaf(e4.w, e4.w, pp);
#pragma unroll
            for (int off = 1; off < 16; off <<= 1) pp += __shfl_xor(pp, off);
            if (gl2 == 0) nlds[s] = pp;
        }
    }
    __syncthreads();

    // ---- per-wave dot rounds (structure identical to verified kernel) ----
    int gl = lane & 15, g = lane >> 4;
    const float4* Yr = (const float4*)(ylds + wv * 256);
    float4 ya = Yr[gl], yb = Yr[gl + 16], yc = Yr[gl + 32], yd = Yr[gl + 48];

    float p = ya.x * ya.x;
    p = fmaf(ya.y, ya.y, p); p = fmaf(ya.z, ya.z, p); p = fmaf(ya.w, ya.w, p);
    p = fmaf(yb.x, yb.x, p); p = fmaf(yb.y, yb.y, p); p = fmaf(yb.z, yb.z, p);
    p = fmaf(yb.w, yb.w, p);
    p = fmaf(yc.x, yc.x, p); p = fmaf(yc.y, yc.y, p); p = fmaf(yc.z, yc.z, p);
    p = fmaf(yc.w, yc.w, p);
    p = fmaf(yd.x, yd.x, p); p = fmaf(yd.y, yd.y, p); p = fmaf(yd.z, yd.z, p);
    p = fmaf(yd.w, yd.w, p);
#pragma unroll
    for (int off = 1; off < 16; off <<= 1) p += __shfl_xor(p, off);
    float na = __fsqrt_rn(p);

    int off_i = jx0 - JCL;                    // >= 0 by monotonicity
    unsigned mm = (unsigned)mball;
    if (g > 0) mm &= mm - 1;
    if (g > 1) mm &= mm - 1;
    if (g > 2) mm &= mm - 1;
    int rounds = (cnt + 3) >> 2;

    double ssum = 0.0;
    for (int r2 = 0; r2 < rounds; r2++) {
        bool val = (mm != 0);
        int s  = val ? (__ffs(mm) - 1) : 0;
        int sl = val ? ((s >> 2) * 20 + off_i + (s & 3)) : 0;
        const float4* Z4 = (const float4*)(slab + sl * 260);
        float4 za = Z4[gl], zb_ = Z4[gl + 16], zc = Z4[gl + 32], zd = Z4[gl + 48];
        float nb2 = nlds[sl];
        float dp = ya.x * za.x;
        dp = fmaf(ya.y, za.y, dp); dp = fmaf(ya.z, za.z, dp);
        dp = fmaf(ya.w, za.w, dp);
        dp = fmaf(yb.x, zb_.x, dp); dp = fmaf(yb.y, zb_.y, dp);
        dp = fmaf(yb.z, zb_.z, dp); dp = fmaf(yb.w, zb_.w, dp);
        dp = fmaf(yc.x, zc.x, dp); dp = fmaf(yc.y, zc.y, dp);
        dp = fmaf(yc.z, zc.z, dp); dp = fmaf(yc.w, zc.w, dp);
        dp = fmaf(yd.x, zd.x, dp); dp = fmaf(yd.y, zd.y, dp);
        dp = fmaf(yd.z, zd.z, dp); dp = fmaf(yd.w, zd.w, dp);
#pragma unroll
        for (int off = 1; off < 16; off <<= 1) dp += __shfl_xor(dp, off);
        float den = fmaxf(na * __fsqrt_rn(nb2), 1e-8f);
        float sim = __fdividef(dp, den);
        if (val) ssum += (double)sim;
        mm &= mm - 1; mm &= mm - 1; mm &= mm - 1; mm &= mm - 1;
    }
    ssum += __shfl_xor(ssum, 16);
    ssum += __shfl_xor(ssum, 32);

    if (lane == 0) { shs[wv] = ssum; shc[wv] = cnt; }
    __syncthreads();
    if (tid == 0) {
        double s = 0.0; int c = 0;
#pragma unroll
        for (int k = 0; k < 14; k++) { s += shs[k]; c += shc[k]; }
        double* slot = acc + (size_t)(bid & (SLOTS - 1)) * 4;
        atomicAdd(&slot[loss * 2],     s);
        atomicAdd(&slot[loss * 2 + 1], (double)c);
    }
}

// ---------------------------------------------------------------------------
// finalize  loss = -(S0/M0 + S1/M1)  (reduce the 128 slots)
// ---------------------------------------------------------------------------
__global__ void fin_k(const double* __restrict__ acc, float* __restrict__ out) {
    int lane = threadIdx.x;   // 64 threads
    double s0 = 0, m0 = 0, s1 = 0, m1 = 0;
    for (int s = lane; s < SLOTS; s += 64) {
        const double* p = acc + (size_t)s * 4;
        s0 += p[0]; m0 += p[1]; s1 += p[2]; m1 += p[3];
    }
#pragma unroll
    for (int off = 32; off; off >>= 1) {
        s0 += __shfl_xor(s0, off); m0 += __shfl_xor(m0, off);
        s1 += __shfl_xor(s1, off); m1 += __shfl_xor(m1, off);
    }
    if (lane == 0) out[0] = (float)(-(s0 / m0 + s1 / m1));
}

extern "C" void kernel_launch(void* const* d_in, const int* in_sizes, int n_in,
                              void* d_out, int out_size, void* d_ws, size_t ws_size,
                              hipStream_t stream) {
    const float* y1 = (const float*)d_in[0];
    const float* y2 = (const float*)d_in[1];
    const float* z1 = (const float*)d_in[2];
    const float* z2 = (const float*)d_in[3];
    const float* g1 = (const float*)d_in[4];
    const float* g2 = (const float*)d_in[5];
    float* out = (float*)d_out;

    double* acc = (double*)d_ws;              // SLOTS*4 doubles = 4 KB
    hipMemsetAsync(acc, 0, SLOTS * 4 * sizeof(double), stream);

    // fused: 8 xcd * 2 loss * 8 b8 * 56 tiles = 7168 blocks x 896 threads
    pairs_k<<<7168, 896, 0, stream>>>(y1, y2, z1, z2, g1, g2, acc);

    fin_k<<<1, 64, 0, stream>>>(acc, out);
}